// Round 2
// baseline (5133.474 us; speedup 1.0000x reference)
//
#include <hip/hip_runtime.h>
#include <hip/hip_bf16.h>
#include <hip/hip_cooperative_groups.h>
#include <stdint.h>

namespace cg = cooperative_groups;

// LSTM T=256, B=64, I=H=O=1024.
// (1) XG = X@Wx4 + b4 as one big bf16 GEMM
// (2) ONE persistent cooperative kernel runs all 256 recurrence steps:
//     W_h resident in LDS, C state in registers, grid.sync() per step.
// (3) Y = Hall@Whq + bq as one GEMM.

typedef __bf16 bf16x8 __attribute__((ext_vector_type(8)));
typedef float  f32x4  __attribute__((ext_vector_type(4)));

#define AS1 __attribute__((address_space(1)))
#define AS3 __attribute__((address_space(3)))

static __device__ __forceinline__ void gload_lds16(const void* g, void* l) {
  __builtin_amdgcn_global_load_lds((const AS1 void*)g, (AS3 void*)l, 16, 0, 0);
}

static __device__ __forceinline__ float sigm(float x) { return 1.f / (1.f + __expf(-x)); }
static __device__ __forceinline__ float tanh_fast(float x) { return 1.f - 2.f / (1.f + __expf(2.f * x)); }

// ---------------- prep kernels ----------------

__global__ void convert_x_kernel(const float* __restrict__ X, __hip_bfloat16* __restrict__ Xbf) {
  size_t i8 = (size_t)(blockIdx.x * 256 + threadIdx.x) * 8;
  float4 a = *(const float4*)(X + i8);
  float4 b = *(const float4*)(X + i8 + 4);
  union { __hip_bfloat16 h[8]; int4 v; } u;
  u.h[0] = __float2bfloat16(a.x); u.h[1] = __float2bfloat16(a.y);
  u.h[2] = __float2bfloat16(a.z); u.h[3] = __float2bfloat16(a.w);
  u.h[4] = __float2bfloat16(b.x); u.h[5] = __float2bfloat16(b.y);
  u.h[6] = __float2bfloat16(b.z); u.h[7] = __float2bfloat16(b.w);
  *(int4*)(Xbf + i8) = u.v;
}

__global__ void init_kernel(const float* __restrict__ H0, const float* __restrict__ C0,
                            const float* __restrict__ bi, const float* __restrict__ bf_,
                            const float* __restrict__ bo, const float* __restrict__ bc,
                            __hip_bfloat16* __restrict__ Hb0, float* __restrict__ b4) {
  int e = blockIdx.x * 256 + threadIdx.x;
  if (e < 65536) {
    Hb0[e] = __float2bfloat16(H0[e]);
  } else {
    int i = e - 65536;
    if (i < 4096) {
      const float* p = (i < 1024) ? bi : (i < 2048) ? bf_ : (i < 3072) ? bo : bc;
      b4[i] = p[i & 1023];
    }
  }
}

struct PackArgs { const float* s[9]; };

// Transposed bf16 pack: dst[n][k] = src[k][n]  (B^T layout for MFMA B-frags)
__global__ void pack_weights_kernel(PackArgs pa, __hip_bfloat16* __restrict__ wxT,
                                    __hip_bfloat16* __restrict__ whT,
                                    __hip_bfloat16* __restrict__ whqT) {
  __shared__ float tile[32][33];
  int mz = blockIdx.z;
  const float* src = pa.s[mz];
  __hip_bfloat16* dst = (mz < 4) ? (wxT + (size_t)mz * 1048576)
                      : (mz < 8) ? (whT + (size_t)(mz - 4) * 1048576)
                                 : whqT;
  int c0 = blockIdx.x * 32, r0 = blockIdx.y * 32;
  int tx = threadIdx.x, ty = threadIdx.y;
#pragma unroll
  for (int i = 0; i < 4; ++i)
    tile[ty + 8 * i][tx] = src[(size_t)(r0 + ty + 8 * i) * 1024 + c0 + tx];
  __syncthreads();
#pragma unroll
  for (int i = 0; i < 4; ++i)
    dst[(size_t)(c0 + ty + 8 * i) * 1024 + r0 + tx] = __float2bfloat16(tile[tx][ty + 8 * i]);
}

// ---------------- big GEMM (phases 1 and 3) ----------------
// C[M][N] = A[M][1024] * B^T[N][1024] + bias ; 128x128 tile, 4 waves, BK=64.
// LDS tiles XOR-swizzled via pre-swizzled global_load_lds source.

template <bool OUT_BF16>
__global__ __launch_bounds__(256) void gemm_bt_kernel(
    const __hip_bfloat16* __restrict__ A,
    const __hip_bfloat16* __restrict__ B,
    const float* __restrict__ bias,
    void* __restrict__ Out, int N) {
  __shared__ char lds[32768];
  char* Alds = lds;
  char* Blds = lds + 16384;
  const int tid = threadIdx.x;
  const int lane = tid & 63, wave = tid >> 6;
  const int wm = wave >> 1, wn = wave & 1;
  const size_t m0 = (size_t)blockIdx.x * 128;
  const size_t n0 = (size_t)blockIdx.y * 128;

  const char* Ag = (const char*)A + m0 * 2048;
  const char* Bg = (const char*)B + n0 * 2048;

  int u_so[4];
#pragma unroll
  for (int c = 0; c < 4; ++c) {
    int u = c * 256 + tid;
    int row = u >> 3, cu = u & 7;
    u_so[c] = row * 2048 + ((cu * 16) ^ ((row & 7) << 4));
  }

  f32x4 acc[4][4] = {};
  const int lr = lane & 15;
  const int lk = (lane >> 4) << 4;
  const int ls = (lane & 7) << 4;

  for (int kt = 0; kt < 16; ++kt) {
    const char* Ak = Ag + kt * 128;
    const char* Bk = Bg + kt * 128;
#pragma unroll
    for (int c = 0; c < 4; ++c) {
      gload_lds16(Ak + u_so[c], Alds + c * 4096 + wave * 1024);
      gload_lds16(Bk + u_so[c], Blds + c * 4096 + wave * 1024);
    }
    __syncthreads();
#pragma unroll
    for (int kk = 0; kk < 2; ++kk) {
      bf16x8 af[4], bfr[4];
#pragma unroll
      for (int m = 0; m < 4; ++m) {
        int row = wm * 64 + m * 16 + lr;
        af[m] = *(const bf16x8*)(Alds + row * 128 + ((kk * 64 + lk) ^ ls));
      }
#pragma unroll
      for (int n = 0; n < 4; ++n) {
        int row = wn * 64 + n * 16 + lr;
        bfr[n] = *(const bf16x8*)(Blds + row * 128 + ((kk * 64 + lk) ^ ls));
      }
#pragma unroll
      for (int m = 0; m < 4; ++m)
#pragma unroll
        for (int n = 0; n < 4; ++n)
          acc[m][n] = __builtin_amdgcn_mfma_f32_16x16x32_bf16(af[m], bfr[n], acc[m][n], 0, 0, 0);
    }
    __syncthreads();
  }

  const size_t crow0 = m0 + wm * 64;
  const size_t ccol0 = n0 + wn * 64;
#pragma unroll
  for (int n = 0; n < 4; ++n) {
    size_t col = ccol0 + n * 16 + lr;
    float bv = bias[col];
#pragma unroll
    for (int m = 0; m < 4; ++m) {
      size_t row0 = crow0 + m * 16 + ((lane >> 4) << 2);
#pragma unroll
      for (int r = 0; r < 4; ++r) {
        float v = acc[m][n][r] + bv;
        size_t o = (row0 + r) * (size_t)N + col;
        if (OUT_BF16) ((__hip_bfloat16*)Out)[o] = __float2bfloat16(v);
        else          ((float*)Out)[o] = v;
      }
    }
  }
}

// ---------------- persistent sequential LSTM ----------------
// 128 blocks x 256 threads, cooperative launch. Block jb owns hidden cols
// [jb*8, jb*8+8) (= 32 gate-cols). W slice (64KB) LDS-resident for all 256
// steps; C state in registers; one grid.sync() per step.

__global__ __launch_bounds__(256) void lstm_persistent_kernel(
    const __hip_bfloat16* __restrict__ XG,    // [16384][4096] = Xb@Wx4 + b4
    const __hip_bfloat16* __restrict__ WhT,   // [4096][1024] transposed
    __hip_bfloat16* __restrict__ Hbuf,        // [257][64][1024]
    const float* __restrict__ C0,             // [64][1024]
    float* __restrict__ outH, float* __restrict__ outC) {
  cg::grid_group grid = cg::this_grid();
  __shared__ char lds[65536 + 64 * 33 * 4];
  char* Wlds = lds;
  float* gates = (float*)(lds + 65536);
  const int tid = threadIdx.x;
  const int lane = tid & 63, wave = tid >> 6;
  const int jb = blockIdx.x;  // 0..127

  // One-time W staging: 32 LDS rows (q*8+rr) x 2048B, XOR-swizzled source.
#pragma unroll
  for (int c = 0; c < 16; ++c) {
    int u = c * 256 + tid;
    int row = u >> 7, cu = u & 127;
    size_t n = (size_t)(row >> 3) * 1024 + (size_t)jb * 8 + (row & 7);
    const char* src = (const char*)(WhT + n * 1024) + ((cu * 16) ^ ((row & 7) << 4));
    gload_lds16(src, Wlds + c * 4096 + wave * 1024);
  }

  // C state in registers: thread owns (b,j) pairs e = i*256+tid.
  float creg[2];
#pragma unroll
  for (int i = 0; i < 2; ++i) {
    int e = i * 256 + tid;
    creg[i] = C0[(size_t)(e >> 3) * 1024 + jb * 8 + (e & 7)];
  }
  __syncthreads();

  const int lr = lane & 15;
  const int lk = (lane >> 4) << 4;
  const int ls = (lane & 7) << 4;

  for (int t = 0; t < 256; ++t) {
    // Prefetch this step's XG gate biases (independent of recurrence) so the
    // loads issue before/under the MFMA chain.
    float xgv[2][4];
#pragma unroll
    for (int i = 0; i < 2; ++i) {
      int e = i * 256 + tid;
      int b = e >> 3, j = e & 7;
      const __hip_bfloat16* xg = XG + ((size_t)t * 64 + b) * 4096 + jb * 8 + j;
      xgv[i][0] = __bfloat162float(xg[0]);
      xgv[i][1] = __bfloat162float(xg[1024]);
      xgv[i][2] = __bfloat162float(xg[2048]);
      xgv[i][3] = __bfloat162float(xg[3072]);
    }

    const char* Hrow = (const char*)(Hbuf + (size_t)t * 65536) + (size_t)(wave * 16 + lr) * 2048;
    f32x4 acc[2] = {};
#pragma unroll
    for (int k = 0; k < 32; ++k) {
      bf16x8 a = *(const bf16x8*)(Hrow + k * 64 + lk);
#pragma unroll
      for (int n = 0; n < 2; ++n) {
        bf16x8 b = *(const bf16x8*)(Wlds + (n * 16 + lr) * 2048 + ((k * 64 + lk) ^ ls));
        acc[n] = __builtin_amdgcn_mfma_f32_16x16x32_bf16(a, b, acc[n], 0, 0, 0);
      }
    }

    // Gate pre-activations to LDS (per-wave-exclusive rows), then exchange.
#pragma unroll
    for (int n = 0; n < 2; ++n)
#pragma unroll
      for (int r = 0; r < 4; ++r)
        gates[(wave * 16 + ((lane >> 4) << 2) + r) * 33 + n * 16 + lr] = acc[n][r];
    __syncthreads();

    __hip_bfloat16* Hnext = Hbuf + (size_t)(t + 1) * 65536;
#pragma unroll
    for (int i = 0; i < 2; ++i) {
      int e = i * 256 + tid;
      int b = e >> 3, j = e & 7;
      int jg = jb * 8 + j;
      float gi = gates[b * 33 + 0  + j] + xgv[i][0];
      float gf = gates[b * 33 + 8  + j] + xgv[i][1];
      float go = gates[b * 33 + 16 + j] + xgv[i][2];
      float gc = gates[b * 33 + 24 + j] + xgv[i][3];
      float I = sigm(gi), F = sigm(gf), O = sigm(go);
      float Ct = tanh_fast(gc);
      float Cn = F * creg[i] + I * Ct;
      creg[i] = Cn;
      float Hn = O * tanh_fast(Cn);
      size_t ci = (size_t)b * 1024 + jg;
      Hnext[ci] = __float2bfloat16(Hn);
      if (t == 255) { outH[ci] = Hn; outC[ci] = Cn; }
    }
    grid.sync();
  }
}

// ---------------- host ----------------

extern "C" void kernel_launch(void* const* d_in, const int* in_sizes, int n_in,
                              void* d_out, int out_size, void* d_ws, size_t ws_size,
                              hipStream_t stream) {
  const float* X   = (const float*)d_in[0];
  const float* H0  = (const float*)d_in[1];
  const float* C0  = (const float*)d_in[2];
  const float* Wxi = (const float*)d_in[3];
  const float* Whi = (const float*)d_in[4];
  const float* bi  = (const float*)d_in[5];
  const float* Wxf = (const float*)d_in[6];
  const float* Whf = (const float*)d_in[7];
  const float* bf  = (const float*)d_in[8];
  const float* Wxo = (const float*)d_in[9];
  const float* Who = (const float*)d_in[10];
  const float* bo  = (const float*)d_in[11];
  const float* Wxc = (const float*)d_in[12];
  const float* Whc = (const float*)d_in[13];
  const float* bc  = (const float*)d_in[14];
  const float* Whq = (const float*)d_in[15];
  const float* bq  = (const float*)d_in[16];

  char* ws = (char*)d_ws;
  size_t off = 0;
  auto alloc = [&](size_t bytes) {
    char* p = ws + off;
    off += (bytes + 255) & ~(size_t)255;
    return p;
  };
  __hip_bfloat16* Xbf  = (__hip_bfloat16*)alloc(16384ull * 1024 * 2);  // 32 MB
  __hip_bfloat16* WxT  = (__hip_bfloat16*)alloc(4096ull * 1024 * 2);   // 8 MB
  __hip_bfloat16* WhT  = (__hip_bfloat16*)alloc(4096ull * 1024 * 2);   // 8 MB
  __hip_bfloat16* WhqT = (__hip_bfloat16*)alloc(1024ull * 1024 * 2);   // 2 MB
  float*          b4   = (float*)alloc(4096 * 4);
  __hip_bfloat16* Hbuf = (__hip_bfloat16*)alloc(257ull * 65536 * 2);   // 32.1 MB
  __hip_bfloat16* XG   = (__hip_bfloat16*)alloc(16384ull * 4096 * 2);  // 128 MB
  (void)ws_size; (void)in_sizes; (void)n_in; (void)out_size;

  convert_x_kernel<<<8192, 256, 0, stream>>>(X, Xbf);
  init_kernel<<<272, 256, 0, stream>>>(H0, C0, bi, bf, bo, bc, Hbuf, b4);
  PackArgs pa;
  pa.s[0] = Wxi; pa.s[1] = Wxf; pa.s[2] = Wxo; pa.s[3] = Wxc;
  pa.s[4] = Whi; pa.s[5] = Whf; pa.s[6] = Who; pa.s[7] = Whc;
  pa.s[8] = Whq;
  pack_weights_kernel<<<dim3(32, 32, 9), dim3(32, 8), 0, stream>>>(pa, WxT, WhT, WhqT);

  gemm_bt_kernel<true><<<dim3(128, 32), 256, 0, stream>>>(Xbf, WxT, b4, XG, 4096);

  float* outY = (float*)d_out;
  float* outH = outY + 16777216;
  float* outC = outH + 65536;

  {
    const __hip_bfloat16* XGc = XG;
    const __hip_bfloat16* WhTc = WhT;
    __hip_bfloat16* Hbufp = Hbuf;
    const float* C0c = C0;
    float* oH = outH;
    float* oC = outC;
    void* args[] = {(void*)&XGc, (void*)&WhTc, (void*)&Hbufp, (void*)&C0c,
                    (void*)&oH, (void*)&oC};
    hipLaunchCooperativeKernel((const void*)lstm_persistent_kernel,
                               dim3(128), dim3(256), args, 0, stream);
  }

  gemm_bt_kernel<false><<<dim3(128, 8), 256, 0, stream>>>(Hbuf + 65536, WhqT, bq, d_out, 1024);
}

// Round 3
// 3245.765 us; speedup vs baseline: 1.5816x; 1.5816x over previous
//
#include <hip/hip_runtime.h>
#include <hip/hip_bf16.h>
#include <stdint.h>

// LSTM T=256, B=64, I=H=O=1024.
// (1) XG = X@Wx4 + b4 as one big bf16 GEMM
// (2) ONE persistent cooperative kernel runs all 256 recurrence steps:
//     64 blocks x 256 thr, W_h slice (128KB) LDS-resident, C in registers.
//     Custom grid barrier: agent-scope coherent H exchange + relaxed
//     agent atomic counter (NO L2 writeback/invalidate, unlike grid.sync).
// (3) Y = Hall@Whq + bq as one GEMM.

typedef __bf16 bf16x8 __attribute__((ext_vector_type(8)));
typedef float  f32x4  __attribute__((ext_vector_type(4)));
typedef unsigned long ulong_t;

#define AS1 __attribute__((address_space(1)))
#define AS3 __attribute__((address_space(3)))

static __device__ __forceinline__ void gload_lds16(const void* g, void* l) {
  __builtin_amdgcn_global_load_lds((const AS1 void*)g, (AS3 void*)l, 16, 0, 0);
}

static __device__ __forceinline__ float sigm(float x) { return 1.f / (1.f + __expf(-x)); }
static __device__ __forceinline__ float tanh_fast(float x) { return 1.f - 2.f / (1.f + __expf(2.f * x)); }

// 16B LLC-coherent load (bypasses possibly-stale per-XCD L2)
static __device__ __forceinline__ bf16x8 coh_load16(const void* p) {
  ulong_t a0 = __hip_atomic_load((const ulong_t*)p,     __ATOMIC_RELAXED, __HIP_MEMORY_SCOPE_AGENT);
  ulong_t a1 = __hip_atomic_load((const ulong_t*)p + 1, __ATOMIC_RELAXED, __HIP_MEMORY_SCOPE_AGENT);
  union { ulong_t u[2]; bf16x8 v; } w;
  w.u[0] = a0; w.u[1] = a1;
  return w.v;
}

static __device__ __forceinline__ float bfbits2f(unsigned short s) {
  union { unsigned int u; float f; } w; w.u = (unsigned int)s << 16; return w.f;
}

// ---------------- prep kernels ----------------

__global__ void convert_x_kernel(const float* __restrict__ X, __hip_bfloat16* __restrict__ Xbf) {
  size_t i8 = (size_t)(blockIdx.x * 256 + threadIdx.x) * 8;
  float4 a = *(const float4*)(X + i8);
  float4 b = *(const float4*)(X + i8 + 4);
  union { __hip_bfloat16 h[8]; int4 v; } u;
  u.h[0] = __float2bfloat16(a.x); u.h[1] = __float2bfloat16(a.y);
  u.h[2] = __float2bfloat16(a.z); u.h[3] = __float2bfloat16(a.w);
  u.h[4] = __float2bfloat16(b.x); u.h[5] = __float2bfloat16(b.y);
  u.h[6] = __float2bfloat16(b.z); u.h[7] = __float2bfloat16(b.w);
  *(int4*)(Xbf + i8) = u.v;
}

__global__ void init_kernel(const float* __restrict__ H0,
                            const float* __restrict__ bi, const float* __restrict__ bf_,
                            const float* __restrict__ bo, const float* __restrict__ bc,
                            __hip_bfloat16* __restrict__ Hb0, float* __restrict__ b4,
                            unsigned int* __restrict__ bar) {
  int e = blockIdx.x * 256 + threadIdx.x;
  if (e < 65536) {
    Hb0[e] = __float2bfloat16(H0[e]);
  } else {
    int i = e - 65536;
    if (i < 4096) {
      const float* p = (i < 1024) ? bi : (i < 2048) ? bf_ : (i < 3072) ? bo : bc;
      b4[i] = p[i & 1023];
    }
    if (i == 4095) *bar = 0u;
  }
}

struct PackArgs { const float* s[9]; };

// Transposed bf16 pack: dst[n][k] = src[k][n]  (B^T layout for MFMA B-frags)
__global__ void pack_weights_kernel(PackArgs pa, __hip_bfloat16* __restrict__ wxT,
                                    __hip_bfloat16* __restrict__ whT,
                                    __hip_bfloat16* __restrict__ whqT) {
  __shared__ float tile[32][33];
  int mz = blockIdx.z;
  const float* src = pa.s[mz];
  __hip_bfloat16* dst = (mz < 4) ? (wxT + (size_t)mz * 1048576)
                      : (mz < 8) ? (whT + (size_t)(mz - 4) * 1048576)
                                 : whqT;
  int c0 = blockIdx.x * 32, r0 = blockIdx.y * 32;
  int tx = threadIdx.x, ty = threadIdx.y;
#pragma unroll
  for (int i = 0; i < 4; ++i)
    tile[ty + 8 * i][tx] = src[(size_t)(r0 + ty + 8 * i) * 1024 + c0 + tx];
  __syncthreads();
#pragma unroll
  for (int i = 0; i < 4; ++i)
    dst[(size_t)(c0 + ty + 8 * i) * 1024 + r0 + tx] = __float2bfloat16(tile[tx][ty + 8 * i]);
}

// ---------------- big GEMM (phases 1 and 3) ----------------
// C[M][N] = A[M][1024] * B^T[N][1024] + bias ; 128x128 tile, 4 waves, BK=64.

template <bool OUT_BF16>
__global__ __launch_bounds__(256) void gemm_bt_kernel(
    const __hip_bfloat16* __restrict__ A,
    const __hip_bfloat16* __restrict__ B,
    const float* __restrict__ bias,
    void* __restrict__ Out, int N) {
  __shared__ char lds[32768];
  char* Alds = lds;
  char* Blds = lds + 16384;
  const int tid = threadIdx.x;
  const int lane = tid & 63, wave = tid >> 6;
  const int wm = wave >> 1, wn = wave & 1;
  const size_t m0 = (size_t)blockIdx.x * 128;
  const size_t n0 = (size_t)blockIdx.y * 128;

  const char* Ag = (const char*)A + m0 * 2048;
  const char* Bg = (const char*)B + n0 * 2048;

  int u_so[4];
#pragma unroll
  for (int c = 0; c < 4; ++c) {
    int u = c * 256 + tid;
    int row = u >> 3, cu = u & 7;
    u_so[c] = row * 2048 + ((cu * 16) ^ ((row & 7) << 4));
  }

  f32x4 acc[4][4] = {};
  const int lr = lane & 15;
  const int lk = (lane >> 4) << 4;
  const int ls = (lane & 7) << 4;

  for (int kt = 0; kt < 16; ++kt) {
    const char* Ak = Ag + kt * 128;
    const char* Bk = Bg + kt * 128;
#pragma unroll
    for (int c = 0; c < 4; ++c) {
      gload_lds16(Ak + u_so[c], Alds + c * 4096 + wave * 1024);
      gload_lds16(Bk + u_so[c], Blds + c * 4096 + wave * 1024);
    }
    __syncthreads();
#pragma unroll
    for (int kk = 0; kk < 2; ++kk) {
      bf16x8 af[4], bfr[4];
#pragma unroll
      for (int m = 0; m < 4; ++m) {
        int row = wm * 64 + m * 16 + lr;
        af[m] = *(const bf16x8*)(Alds + row * 128 + ((kk * 64 + lk) ^ ls));
      }
#pragma unroll
      for (int n = 0; n < 4; ++n) {
        int row = wn * 64 + n * 16 + lr;
        bfr[n] = *(const bf16x8*)(Blds + row * 128 + ((kk * 64 + lk) ^ ls));
      }
#pragma unroll
      for (int m = 0; m < 4; ++m)
#pragma unroll
        for (int n = 0; n < 4; ++n)
          acc[m][n] = __builtin_amdgcn_mfma_f32_16x16x32_bf16(af[m], bfr[n], acc[m][n], 0, 0, 0);
    }
    __syncthreads();
  }

  const size_t crow0 = m0 + wm * 64;
  const size_t ccol0 = n0 + wn * 64;
#pragma unroll
  for (int n = 0; n < 4; ++n) {
    size_t col = ccol0 + n * 16 + lr;
    float bv = bias[col];
#pragma unroll
    for (int m = 0; m < 4; ++m) {
      size_t row0 = crow0 + m * 16 + ((lane >> 4) << 2);
#pragma unroll
      for (int r = 0; r < 4; ++r) {
        float v = acc[m][n][r] + bv;
        size_t o = (row0 + r) * (size_t)N + col;
        if (OUT_BF16) ((__hip_bfloat16*)Out)[o] = __float2bfloat16(v);
        else          ((float*)Out)[o] = v;
      }
    }
  }
}

// ---------------- persistent sequential LSTM ----------------
// 64 blocks x 256 threads (cooperative). Block jb owns hidden cols
// [jb*16, jb*16+16) -> 64 gate cols {q*1024 + jb*16 + jc}. W slice 128KB
// LDS-resident all 256 steps. Wave w = batch rows [16w,16w+16); per k-iter
// one H A-frag (coherent 16B load) feeds 4 gate-tile MFMAs.

__global__ __launch_bounds__(256) void lstm_persistent_kernel(
    const __hip_bfloat16* __restrict__ XG,    // [16384][4096] = Xb@Wx4 + b4
    const __hip_bfloat16* __restrict__ WhT,   // [4096][1024] transposed
    __hip_bfloat16* __restrict__ Hbuf,        // [257][64][1024]
    const float* __restrict__ C0,             // [64][1024]
    float* __restrict__ outH, float* __restrict__ outC,
    unsigned int* __restrict__ bar) {
  __shared__ char lds[131072 + 64 * 68 * 4];
  char* Wlds = lds;
  float* gates = (float*)(lds + 131072);   // [64 batch][68] (4 gates x 16 jc, pad)
  const int tid = threadIdx.x;
  const int lane = tid & 63, wave = tid >> 6;
  const int jb = blockIdx.x;  // 0..63

  // One-time W staging: LDS row rr = q*16 + jc  (64 rows x 2048B), XOR-swizzled.
#pragma unroll
  for (int c = 0; c < 32; ++c) {
    int u = c * 256 + tid;
    int row = u >> 7, cu = u & 127;
    size_t n = (size_t)(row >> 4) * 1024 + (size_t)jb * 16 + (row & 15);
    const char* src = (const char*)(WhT + n * 1024) + ((cu * 16) ^ ((row & 7) << 4));
    gload_lds16(src, Wlds + c * 4096 + wave * 1024);
  }

  // C state in registers: thread owns (b = tid>>2, jc0 = (tid&3)*4 .. +4)
  const int b = tid >> 2;
  const int jc0 = (tid & 3) * 4;
  f32x4 creg = *(const f32x4*)(C0 + (size_t)b * 1024 + jb * 16 + jc0);
  __syncthreads();

  const int lr = lane & 15;
  const int lk = (lane >> 4) << 4;
  const int ls = (lane & 7) << 4;
  const char* xgbase = (const char*)XG + (size_t)b * 8192 + ((size_t)jb * 16 + jc0) * 2;

  for (int t = 0; t < 256; ++t) {
    // Prefetch this step's XG gate biases (plain loads; XG read-only).
    float xgv[4][4];
#pragma unroll
    for (int q = 0; q < 4; ++q) {
      ushort4 xv = *(const ushort4*)(xgbase + (size_t)t * 524288 + q * 2048);
      xgv[q][0] = bfbits2f(xv.x); xgv[q][1] = bfbits2f(xv.y);
      xgv[q][2] = bfbits2f(xv.z); xgv[q][3] = bfbits2f(xv.w);
    }

    // H @ W for this block's 64 gate cols; H via LLC-coherent loads.
    const char* Hrow = (const char*)(Hbuf + (size_t)t * 65536) + (size_t)(wave * 16 + lr) * 2048 + lk;
    f32x4 acc[4] = {};
#pragma unroll
    for (int k = 0; k < 32; ++k) {
      bf16x8 a = coh_load16(Hrow + k * 64);
#pragma unroll
      for (int q = 0; q < 4; ++q) {
        bf16x8 bb = *(const bf16x8*)(Wlds + (q * 16 + lr) * 2048 + ((k * 64 + lk) ^ ls));
        acc[q] = __builtin_amdgcn_mfma_f32_16x16x32_bf16(a, bb, acc[q], 0, 0, 0);
      }
    }

    // Gate pre-activations -> LDS exchange.
#pragma unroll
    for (int q = 0; q < 4; ++q)
#pragma unroll
      for (int r = 0; r < 4; ++r)
        gates[(wave * 16 + ((lane >> 4) << 2) + r) * 68 + q * 16 + lr] = acc[q][r];
    __syncthreads();

    // Cell update for (b, jc0..jc0+3).
    const float* grow = gates + b * 68;
    f32x4 gI = *(const f32x4*)(grow + 0 + jc0);
    f32x4 gF = *(const f32x4*)(grow + 16 + jc0);
    f32x4 gO = *(const f32x4*)(grow + 32 + jc0);
    f32x4 gC = *(const f32x4*)(grow + 48 + jc0);
    union { unsigned short s[4]; ulong_t u; } hp;
    f32x4 oh, oc;
#pragma unroll
    for (int jj = 0; jj < 4; ++jj) {
      float I = sigm(gI[jj] + xgv[0][jj]);
      float F = sigm(gF[jj] + xgv[1][jj]);
      float O = sigm(gO[jj] + xgv[2][jj]);
      float Ct = tanh_fast(gC[jj] + xgv[3][jj]);
      float Cn = F * creg[jj] + I * Ct;
      creg[jj] = Cn;
      float Hn = O * tanh_fast(Cn);
      __hip_bfloat16 hb = __float2bfloat16(Hn);
      hp.s[jj] = *(unsigned short*)&hb;
      oh[jj] = Hn; oc[jj] = Cn;
    }
    // Publish H chunk (LLC-coherent write-through).
    __hip_atomic_store((ulong_t*)((char*)(Hbuf + (size_t)(t + 1) * 65536) +
                                  (size_t)b * 2048 + ((size_t)jb * 16 + jc0) * 2),
                       hp.u, __ATOMIC_RELAXED, __HIP_MEMORY_SCOPE_AGENT);
    if (t == 255) {
      *(f32x4*)(outH + (size_t)b * 1024 + jb * 16 + jc0) = oh;
      *(f32x4*)(outC + (size_t)b * 1024 + jb * 16 + jc0) = oc;
    }

    // Grid barrier: syncthreads drains this block's stores (vmcnt 0), then
    // one relaxed agent atomicAdd per block; tid0 spins on LLC counter.
    __syncthreads();
    if (tid == 0) {
      __hip_atomic_fetch_add(bar, 1u, __ATOMIC_RELAXED, __HIP_MEMORY_SCOPE_AGENT);
      unsigned int target = 64u * (unsigned int)(t + 1);
      while (__hip_atomic_load(bar, __ATOMIC_RELAXED, __HIP_MEMORY_SCOPE_AGENT) < target)
        __builtin_amdgcn_s_sleep(1);
    }
    __syncthreads();
    asm volatile("" ::: "memory");
  }
}

// ---------------- host ----------------

extern "C" void kernel_launch(void* const* d_in, const int* in_sizes, int n_in,
                              void* d_out, int out_size, void* d_ws, size_t ws_size,
                              hipStream_t stream) {
  const float* X   = (const float*)d_in[0];
  const float* H0  = (const float*)d_in[1];
  const float* C0  = (const float*)d_in[2];
  const float* Wxi = (const float*)d_in[3];
  const float* Whi = (const float*)d_in[4];
  const float* bi  = (const float*)d_in[5];
  const float* Wxf = (const float*)d_in[6];
  const float* Whf = (const float*)d_in[7];
  const float* bf  = (const float*)d_in[8];
  const float* Wxo = (const float*)d_in[9];
  const float* Who = (const float*)d_in[10];
  const float* bo  = (const float*)d_in[11];
  const float* Wxc = (const float*)d_in[12];
  const float* Whc = (const float*)d_in[13];
  const float* bc  = (const float*)d_in[14];
  const float* Whq = (const float*)d_in[15];
  const float* bq  = (const float*)d_in[16];

  char* ws = (char*)d_ws;
  size_t off = 0;
  auto alloc = [&](size_t bytes) {
    char* p = ws + off;
    off += (bytes + 255) & ~(size_t)255;
    return p;
  };
  __hip_bfloat16* Xbf  = (__hip_bfloat16*)alloc(16384ull * 1024 * 2);  // 32 MB
  __hip_bfloat16* WxT  = (__hip_bfloat16*)alloc(4096ull * 1024 * 2);   // 8 MB
  __hip_bfloat16* WhT  = (__hip_bfloat16*)alloc(4096ull * 1024 * 2);   // 8 MB
  __hip_bfloat16* WhqT = (__hip_bfloat16*)alloc(1024ull * 1024 * 2);   // 2 MB
  float*          b4   = (float*)alloc(4096 * 4);
  unsigned int*   bar  = (unsigned int*)alloc(256);
  __hip_bfloat16* Hbuf = (__hip_bfloat16*)alloc(257ull * 65536 * 2);   // 32.1 MB
  __hip_bfloat16* XG   = (__hip_bfloat16*)alloc(16384ull * 4096 * 2);  // 128 MB
  (void)ws_size; (void)in_sizes; (void)n_in; (void)out_size;

  convert_x_kernel<<<8192, 256, 0, stream>>>(X, Xbf);
  init_kernel<<<272, 256, 0, stream>>>(H0, bi, bf, bo, bc, Hbuf, b4, bar);
  PackArgs pa;
  pa.s[0] = Wxi; pa.s[1] = Wxf; pa.s[2] = Wxo; pa.s[3] = Wxc;
  pa.s[4] = Whi; pa.s[5] = Whf; pa.s[6] = Who; pa.s[7] = Whc;
  pa.s[8] = Whq;
  pack_weights_kernel<<<dim3(32, 32, 9), dim3(32, 8), 0, stream>>>(pa, WxT, WhT, WhqT);

  gemm_bt_kernel<true><<<dim3(128, 32), 256, 0, stream>>>(Xbf, WxT, b4, XG, 4096);

  float* outY = (float*)d_out;
  float* outH = outY + 16777216;
  float* outC = outH + 65536;

  {
    const __hip_bfloat16* XGc = XG;
    const __hip_bfloat16* WhTc = WhT;
    __hip_bfloat16* Hbufp = Hbuf;
    const float* C0c = C0;
    float* oH = outH;
    float* oC = outC;
    unsigned int* barp = bar;
    void* args[] = {(void*)&XGc, (void*)&WhTc, (void*)&Hbufp, (void*)&C0c,
                    (void*)&oH, (void*)&oC, (void*)&barp};
    hipLaunchCooperativeKernel((const void*)lstm_persistent_kernel,
                               dim3(64), dim3(256), args, 0, stream);
  }

  gemm_bt_kernel<false><<<dim3(128, 8), 256, 0, stream>>>(Hbuf + 65536, WhqT, bq, d_out, 1024);
}

// Round 7
// 2837.359 us; speedup vs baseline: 1.8092x; 1.1439x over previous
//
#include <hip/hip_runtime.h>
#include <hip/hip_bf16.h>
#include <stdint.h>

// LSTM T=256, B=64, I=H=O=1024.
// (1) XG = X@Wx4 + b4 as one big bf16 GEMM
// (2) ONE persistent cooperative kernel runs all 256 recurrence steps:
//     64 blocks x 256 thr, W_h slice (128KB) LDS-resident, C in registers.
//     H exchange via agent-scope coherent loads/stores (LLC, L2-bypass).
//     Round-7: depth-2 pipelined H loads in groups of 8 (compiler-managed
//     waits; register reuse is the compiler's problem, not asm). VGPR
//     capped at 256 via __launch_bounds__(256,2) so cooperative-launch
//     occupancy validation cannot reject the kernel (rounds 5/6 lesson).
// (3) Y = Hall@Whq + bq as one GEMM.

typedef __bf16 bf16x8 __attribute__((ext_vector_type(8)));
typedef float  f32x4  __attribute__((ext_vector_type(4)));
typedef unsigned long ulong_t;

#define AS1 __attribute__((address_space(1)))
#define AS3 __attribute__((address_space(3)))

static __device__ __forceinline__ void gload_lds16(const void* g, void* l) {
  __builtin_amdgcn_global_load_lds((const AS1 void*)g, (AS3 void*)l, 16, 0, 0);
}

static __device__ __forceinline__ float sigm(float x) { return 1.f / (1.f + __expf(-x)); }
static __device__ __forceinline__ float tanh_fast(float x) { return 1.f - 2.f / (1.f + __expf(2.f * x)); }

// 16B LLC-coherent load (bypasses possibly-stale per-XCD L2)
static __device__ __forceinline__ bf16x8 coh_load16(const void* p) {
  ulong_t a0 = __hip_atomic_load((const ulong_t*)p,     __ATOMIC_RELAXED, __HIP_MEMORY_SCOPE_AGENT);
  ulong_t a1 = __hip_atomic_load((const ulong_t*)p + 1, __ATOMIC_RELAXED, __HIP_MEMORY_SCOPE_AGENT);
  union { ulong_t u[2]; bf16x8 v; } w;
  w.u[0] = a0; w.u[1] = a1;
  return w.v;
}

static __device__ __forceinline__ float bfbits2f(unsigned short s) {
  union { unsigned int u; float f; } w; w.u = (unsigned int)s << 16; return w.f;
}

// ---------------- prep kernels ----------------

__global__ void convert_x_kernel(const float* __restrict__ X, __hip_bfloat16* __restrict__ Xbf) {
  size_t i8 = (size_t)(blockIdx.x * 256 + threadIdx.x) * 8;
  float4 a = *(const float4*)(X + i8);
  float4 b = *(const float4*)(X + i8 + 4);
  union { __hip_bfloat16 h[8]; int4 v; } u;
  u.h[0] = __float2bfloat16(a.x); u.h[1] = __float2bfloat16(a.y);
  u.h[2] = __float2bfloat16(a.z); u.h[3] = __float2bfloat16(a.w);
  u.h[4] = __float2bfloat16(b.x); u.h[5] = __float2bfloat16(b.y);
  u.h[6] = __float2bfloat16(b.z); u.h[7] = __float2bfloat16(b.w);
  *(int4*)(Xbf + i8) = u.v;
}

__global__ void init_kernel(const float* __restrict__ H0,
                            const float* __restrict__ bi, const float* __restrict__ bf_,
                            const float* __restrict__ bo, const float* __restrict__ bc,
                            __hip_bfloat16* __restrict__ Hb0, float* __restrict__ b4,
                            unsigned int* __restrict__ bar) {
  int e = blockIdx.x * 256 + threadIdx.x;
  if (e < 65536) {
    Hb0[e] = __float2bfloat16(H0[e]);
  } else {
    int i = e - 65536;
    if (i < 4096) {
      const float* p = (i < 1024) ? bi : (i < 2048) ? bf_ : (i < 3072) ? bo : bc;
      b4[i] = p[i & 1023];
    }
    if (i == 4095) *bar = 0u;
  }
}

struct PackArgs { const float* s[9]; };

// Transposed bf16 pack: dst[n][k] = src[k][n]  (B^T layout for MFMA B-frags)
__global__ void pack_weights_kernel(PackArgs pa, __hip_bfloat16* __restrict__ wxT,
                                    __hip_bfloat16* __restrict__ whT,
                                    __hip_bfloat16* __restrict__ whqT) {
  __shared__ float tile[32][33];
  int mz = blockIdx.z;
  const float* src = pa.s[mz];
  __hip_bfloat16* dst = (mz < 4) ? (wxT + (size_t)mz * 1048576)
                      : (mz < 8) ? (whT + (size_t)(mz - 4) * 1048576)
                                 : whqT;
  int c0 = blockIdx.x * 32, r0 = blockIdx.y * 32;
  int tx = threadIdx.x, ty = threadIdx.y;
#pragma unroll
  for (int i = 0; i < 4; ++i)
    tile[ty + 8 * i][tx] = src[(size_t)(r0 + ty + 8 * i) * 1024 + c0 + tx];
  __syncthreads();
#pragma unroll
  for (int i = 0; i < 4; ++i)
    dst[(size_t)(c0 + ty + 8 * i) * 1024 + r0 + tx] = __float2bfloat16(tile[tx][ty + 8 * i]);
}

// ---------------- big GEMM (phases 1 and 3) ----------------
// C[M][N] = A[M][1024] * B^T[N][1024] + bias ; 128x128 tile, 4 waves, BK=64.

template <bool OUT_BF16>
__global__ __launch_bounds__(256) void gemm_bt_kernel(
    const __hip_bfloat16* __restrict__ A,
    const __hip_bfloat16* __restrict__ B,
    const float* __restrict__ bias,
    void* __restrict__ Out, int N) {
  __shared__ char lds[32768];
  char* Alds = lds;
  char* Blds = lds + 16384;
  const int tid = threadIdx.x;
  const int lane = tid & 63, wave = tid >> 6;
  const int wm = wave >> 1, wn = wave & 1;
  const size_t m0 = (size_t)blockIdx.x * 128;
  const size_t n0 = (size_t)blockIdx.y * 128;

  const char* Ag = (const char*)A + m0 * 2048;
  const char* Bg = (const char*)B + n0 * 2048;

  int u_so[4];
#pragma unroll
  for (int c = 0; c < 4; ++c) {
    int u = c * 256 + tid;
    int row = u >> 3, cu = u & 7;
    u_so[c] = row * 2048 + ((cu * 16) ^ ((row & 7) << 4));
  }

  f32x4 acc[4][4] = {};
  const int lr = lane & 15;
  const int lk = (lane >> 4) << 4;
  const int ls = (lane & 7) << 4;

  for (int kt = 0; kt < 16; ++kt) {
    const char* Ak = Ag + kt * 128;
    const char* Bk = Bg + kt * 128;
#pragma unroll
    for (int c = 0; c < 4; ++c) {
      gload_lds16(Ak + u_so[c], Alds + c * 4096 + wave * 1024);
      gload_lds16(Bk + u_so[c], Blds + c * 4096 + wave * 1024);
    }
    __syncthreads();
#pragma unroll
    for (int kk = 0; kk < 2; ++kk) {
      bf16x8 af[4], bfr[4];
#pragma unroll
      for (int m = 0; m < 4; ++m) {
        int row = wm * 64 + m * 16 + lr;
        af[m] = *(const bf16x8*)(Alds + row * 128 + ((kk * 64 + lk) ^ ls));
      }
#pragma unroll
      for (int n = 0; n < 4; ++n) {
        int row = wn * 64 + n * 16 + lr;
        bfr[n] = *(const bf16x8*)(Blds + row * 128 + ((kk * 64 + lk) ^ ls));
      }
#pragma unroll
      for (int m = 0; m < 4; ++m)
#pragma unroll
        for (int n = 0; n < 4; ++n)
          acc[m][n] = __builtin_amdgcn_mfma_f32_16x16x32_bf16(af[m], bfr[n], acc[m][n], 0, 0, 0);
    }
    __syncthreads();
  }

  const size_t crow0 = m0 + wm * 64;
  const size_t ccol0 = n0 + wn * 64;
#pragma unroll
  for (int n = 0; n < 4; ++n) {
    size_t col = ccol0 + n * 16 + lr;
    float bv = bias[col];
#pragma unroll
    for (int m = 0; m < 4; ++m) {
      size_t row0 = crow0 + m * 16 + ((lane >> 4) << 2);
#pragma unroll
      for (int r = 0; r < 4; ++r) {
        float v = acc[m][n][r] + bv;
        size_t o = (row0 + r) * (size_t)N + col;
        if (OUT_BF16) ((__hip_bfloat16*)Out)[o] = __float2bfloat16(v);
        else          ((float*)Out)[o] = v;
      }
    }
  }
}

// ---------------- persistent sequential LSTM ----------------
// 64 blocks x 256 threads (cooperative). Block jb owns hidden cols
// [jb*16, jb*16+16) -> 64 gate cols. W slice 128KB LDS-resident. Wave w =
// batch rows [16w,16w+16). Per step: H loads pipelined depth-2 in groups
// of 8 (16 issued up front, 8 reissued under each MFMA group), 128 MFMAs,
// gates LDS exchange, cell update, agent publish, grid barrier.
// __launch_bounds__(256,2) caps VGPR at 256: rounds 5/6 showed the
// cooperative launch is cleanly REJECTED when the kernel exceeds that.

__global__ __launch_bounds__(256, 2) void lstm_persistent_kernel(
    const __hip_bfloat16* __restrict__ XG,    // [16384][4096] = Xb@Wx4 + b4
    const __hip_bfloat16* __restrict__ WhT,   // [4096][1024] transposed
    __hip_bfloat16* __restrict__ Hbuf,        // [257][64][1024]
    const float* __restrict__ C0,             // [64][1024]
    float* __restrict__ outH, float* __restrict__ outC,
    unsigned int* __restrict__ bar) {
  __shared__ char lds[131072 + 64 * 68 * 4];
  char* Wlds = lds;
  float* gates = (float*)(lds + 131072);   // [64 batch][68] (4 gates x 16 jc, pad)
  const int tid = threadIdx.x;
  const int lane = tid & 63, wave = tid >> 6;
  const int jb = blockIdx.x;  // 0..63

  // One-time W staging: LDS row rr = q*16 + jc  (64 rows x 2048B), XOR-swizzled.
#pragma unroll
  for (int c = 0; c < 32; ++c) {
    int u = c * 256 + tid;
    int row = u >> 7, cu = u & 127;
    size_t n = (size_t)(row >> 4) * 1024 + (size_t)jb * 16 + (row & 15);
    const char* src = (const char*)(WhT + n * 1024) + ((cu * 16) ^ ((row & 7) << 4));
    gload_lds16(src, Wlds + c * 4096 + wave * 1024);
  }

  // C state in registers: thread owns (b = tid>>2, jc0 = (tid&3)*4 .. +4)
  const int b = tid >> 2;
  const int jc0 = (tid & 3) * 4;
  f32x4 creg = *(const f32x4*)(C0 + (size_t)b * 1024 + jb * 16 + jc0);
  __syncthreads();

  const int lr = lane & 15;
  const int lk = (lane >> 4) << 4;
  const int ls = (lane & 7) << 4;
  const char* xgbase = (const char*)XG + (size_t)b * 8192 + ((size_t)jb * 16 + jc0) * 2;

#define WFRAG(k, q) (*(const bf16x8*)(Wlds + ((q) * 16 + lr) * 2048 + (((k) * 64 + lk) ^ ls)))
#define COMPUTE(hb_, k0)                                                          \
  _Pragma("unroll")                                                               \
  for (int kk = 0; kk < 8; ++kk) {                                                \
    _Pragma("unroll")                                                             \
    for (int q = 0; q < 4; ++q)                                                   \
      acc[q] = __builtin_amdgcn_mfma_f32_16x16x32_bf16(hb_[kk], WFRAG(k0 + kk, q),\
                                                       acc[q], 0, 0, 0);          \
  }

  for (int t = 0; t < 256; ++t) {
    // This step's XG gate biases (plain loads; XG read-only).
    float xgv[4][4];
#pragma unroll
    for (int q = 0; q < 4; ++q) {
      ushort4 xv = *(const ushort4*)(xgbase + (size_t)t * 524288 + q * 2048);
      xgv[q][0] = bfbits2f(xv.x); xgv[q][1] = bfbits2f(xv.y);
      xgv[q][2] = bfbits2f(xv.z); xgv[q][3] = bfbits2f(xv.w);
    }

    const char* Hrow = (const char*)(Hbuf + (size_t)t * 65536) +
                       (size_t)(wave * 16 + lr) * 2048 + lk;

    // Depth-2 pipelined coherent H loads, groups of 8. Register reuse is
    // compiler-managed (C level, not asm) -> waits are always correct;
    // 8 loads stay in flight under each 32-MFMA group.
    bf16x8 ha[8], hb[8];
#pragma unroll
    for (int j = 0; j < 8; ++j) ha[j] = coh_load16(Hrow + j * 64);
#pragma unroll
    for (int j = 0; j < 8; ++j) hb[j] = coh_load16(Hrow + 512 + j * 64);

    f32x4 acc[4] = {};
    COMPUTE(ha, 0)
#pragma unroll
    for (int j = 0; j < 8; ++j) ha[j] = coh_load16(Hrow + 1024 + j * 64);
    COMPUTE(hb, 8)
#pragma unroll
    for (int j = 0; j < 8; ++j) hb[j] = coh_load16(Hrow + 1536 + j * 64);
    COMPUTE(ha, 16)
    COMPUTE(hb, 24)

    // Gate pre-activations -> LDS exchange.
#pragma unroll
    for (int q = 0; q < 4; ++q)
#pragma unroll
      for (int r = 0; r < 4; ++r)
        gates[(wave * 16 + ((lane >> 4) << 2) + r) * 68 + q * 16 + lr] = acc[q][r];
    __syncthreads();

    // Cell update for (b, jc0..jc0+3).
    const float* grow = gates + b * 68;
    f32x4 gI = *(const f32x4*)(grow + 0 + jc0);
    f32x4 gF = *(const f32x4*)(grow + 16 + jc0);
    f32x4 gO = *(const f32x4*)(grow + 32 + jc0);
    f32x4 gC = *(const f32x4*)(grow + 48 + jc0);
    union { unsigned short s[4]; ulong_t u; } hp;
    f32x4 oh, oc;
#pragma unroll
    for (int jj = 0; jj < 4; ++jj) {
      float I = sigm(gI[jj] + xgv[0][jj]);
      float F = sigm(gF[jj] + xgv[1][jj]);
      float O = sigm(gO[jj] + xgv[2][jj]);
      float Ct = tanh_fast(gC[jj] + xgv[3][jj]);
      float Cn = F * creg[jj] + I * Ct;
      creg[jj] = Cn;
      float Hn = O * tanh_fast(Cn);
      __hip_bfloat16 hbv = __float2bfloat16(Hn);
      hp.s[jj] = *(unsigned short*)&hbv;
      oh[jj] = Hn; oc[jj] = Cn;
    }
    // Publish H chunk (agent-coherent store to LLC).
    __hip_atomic_store((ulong_t*)((char*)(Hbuf + (size_t)(t + 1) * 65536) +
                                  (size_t)b * 2048 + ((size_t)jb * 16 + jc0) * 2),
                       hp.u, __ATOMIC_RELAXED, __HIP_MEMORY_SCOPE_AGENT);
    if (t == 255) {
      *(f32x4*)(outH + (size_t)b * 1024 + jb * 16 + jc0) = oh;
      *(f32x4*)(outC + (size_t)b * 1024 + jb * 16 + jc0) = oc;
    }

    // Grid barrier: syncthreads drains this block's stores (vmcnt 0), then
    // one relaxed agent atomicAdd per block; tid0 spins on LLC counter.
    __syncthreads();
    if (tid == 0) {
      __hip_atomic_fetch_add(bar, 1u, __ATOMIC_RELAXED, __HIP_MEMORY_SCOPE_AGENT);
      unsigned int target = 64u * (unsigned int)(t + 1);
      while (__hip_atomic_load(bar, __ATOMIC_RELAXED, __HIP_MEMORY_SCOPE_AGENT) < target)
        __builtin_amdgcn_s_sleep(1);
    }
    __syncthreads();
    asm volatile("" ::: "memory");
  }
#undef COMPUTE
#undef WFRAG
}

// ---------------- host ----------------

extern "C" void kernel_launch(void* const* d_in, const int* in_sizes, int n_in,
                              void* d_out, int out_size, void* d_ws, size_t ws_size,
                              hipStream_t stream) {
  const float* X   = (const float*)d_in[0];
  const float* H0  = (const float*)d_in[1];
  const float* C0  = (const float*)d_in[2];
  const float* Wxi = (const float*)d_in[3];
  const float* Whi = (const float*)d_in[4];
  const float* bi  = (const float*)d_in[5];
  const float* Wxf = (const float*)d_in[6];
  const float* Whf = (const float*)d_in[7];
  const float* bf  = (const float*)d_in[8];
  const float* Wxo = (const float*)d_in[9];
  const float* Who = (const float*)d_in[10];
  const float* bo  = (const float*)d_in[11];
  const float* Wxc = (const float*)d_in[12];
  const float* Whc = (const float*)d_in[13];
  const float* bc  = (const float*)d_in[14];
  const float* Whq = (const float*)d_in[15];
  const float* bq  = (const float*)d_in[16];

  char* ws = (char*)d_ws;
  size_t off = 0;
  auto alloc = [&](size_t bytes) {
    char* p = ws + off;
    off += (bytes + 255) & ~(size_t)255;
    return p;
  };
  __hip_bfloat16* Xbf  = (__hip_bfloat16*)alloc(16384ull * 1024 * 2);  // 32 MB
  __hip_bfloat16* WxT  = (__hip_bfloat16*)alloc(4096ull * 1024 * 2);   // 8 MB
  __hip_bfloat16* WhT  = (__hip_bfloat16*)alloc(4096ull * 1024 * 2);   // 8 MB
  __hip_bfloat16* WhqT = (__hip_bfloat16*)alloc(1024ull * 1024 * 2);   // 2 MB
  float*          b4   = (float*)alloc(4096 * 4);
  unsigned int*   bar  = (unsigned int*)alloc(256);
  __hip_bfloat16* Hbuf = (__hip_bfloat16*)alloc(257ull * 65536 * 2);   // 32.1 MB
  __hip_bfloat16* XG   = (__hip_bfloat16*)alloc(16384ull * 4096 * 2);  // 128 MB
  (void)ws_size; (void)in_sizes; (void)n_in; (void)out_size;

  convert_x_kernel<<<8192, 256, 0, stream>>>(X, Xbf);
  init_kernel<<<272, 256, 0, stream>>>(H0, bi, bf, bo, bc, Hbuf, b4, bar);
  PackArgs pa;
  pa.s[0] = Wxi; pa.s[1] = Wxf; pa.s[2] = Wxo; pa.s[3] = Wxc;
  pa.s[4] = Whi; pa.s[5] = Whf; pa.s[6] = Who; pa.s[7] = Whc;
  pa.s[8] = Whq;
  pack_weights_kernel<<<dim3(32, 32, 9), dim3(32, 8), 0, stream>>>(pa, WxT, WhT, WhqT);

  gemm_bt_kernel<true><<<dim3(128, 32), 256, 0, stream>>>(Xbf, WxT, b4, XG, 4096);

  float* outY = (float*)d_out;
  float* outH = outY + 16777216;
  float* outC = outH + 65536;

  {
    const __hip_bfloat16* XGc = XG;
    const __hip_bfloat16* WhTc = WhT;
    __hip_bfloat16* Hbufp = Hbuf;
    const float* C0c = C0;
    float* oH = outH;
    float* oC = outC;
    unsigned int* barp = bar;
    void* args[] = {(void*)&XGc, (void*)&WhTc, (void*)&Hbufp, (void*)&C0c,
                    (void*)&oH, (void*)&oC, (void*)&barp};
    hipLaunchCooperativeKernel((const void*)lstm_persistent_kernel,
                               dim3(64), dim3(256), args, 0, stream);
  }

  gemm_bt_kernel<false><<<dim3(128, 8), 256, 0, stream>>>(Hbuf + 65536, WhqT, bq, d_out, 1024);
}